// Round 5
// baseline (271.558 us; speedup 1.0000x reference)
//
#include <hip/hip_runtime.h>
#include <hip/hip_bf16.h>

typedef __hip_bfloat16 bf16;

#define L_AG 5
#define C_CH 16
#define H_SZ 256
#define W_SZ 256
#define HW_SZ (H_SZ * W_SZ)

// dtype-polymorphic load/store helpers
__device__ __forceinline__ float ldf(const float* p) { return *p; }
__device__ __forceinline__ float ldf(const bf16* p)  { return __bfloat162float(*p); }
__device__ __forceinline__ void  stf(float* p, float v) { *p = v; }
__device__ __forceinline__ void  stf(bf16* p, float v)  { *p = __float2bfloat16(v); }

// Runtime dtype detector: looks at even-indexed uint16 words of x.
// bf16 ~N(0,1): exponent field < 0x90 always (|v| >= 2^17 impossible).
// fp32 read as words: even words = random mantissa bits -> ~43% have exp >= 0x90.
__global__ void dtype_detect(const unsigned short* __restrict__ xw, int* __restrict__ flag) {
    __shared__ int cnt;
    if (threadIdx.x == 0) cnt = 0;
    __syncthreads();
    int h = 0;
    for (int t = threadIdx.x; t < 512; t += 256) {
        const unsigned short w = xw[2 * t];
        const int e = (w >> 7) & 0xFF;
        h += (e >= 0x90) ? 1 : 0;
    }
    atomicAdd(&cnt, h);
    __syncthreads();
    if (threadIdx.x == 0) flag[0] = (cnt >= 16) ? 1 : 0;  // 1 = fp32, 0 = bf16
}

// Inverse-affine taps for neighbor j as pair offsets (po0: row y0, po1: row
// y1, both at column base cx0p=min(cx0,W-2); the partner element is po+1)
// plus remapped bilinear weights (aw*lo + bw*hi per row). Exactly reproduces
// clamp+validity semantics:
//   interior: aw=w_left, bw=w_right
//   x0==255 : clamped value lives in HI slot -> bw=w00 (w01 already 0)
//   x0==-1  : clamped value lives in LO slot -> aw=w01 (w00 already 0)
__device__ __forceinline__ void tap_params(
    const float (*minv)[6], int j, float px, float py,
    int& po0, int& po1, float& aw0, float& bw0, float& aw1, float& bw1)
{
    const float m0 = minv[j][0], m1 = minv[j][1], m2 = minv[j][2];
    const float m3 = minv[j][3], m4 = minv[j][4], m5 = minv[j][5];
    const float sx = m0 * px + m1 * py + m2;
    const float sy = m3 * px + m4 * py + m5;
    const float fx0 = floorf(sx), fy0 = floorf(sy);
    const int x0 = (int)fx0, y0 = (int)fy0;
    const float wx1 = sx - fx0, wy1 = sy - fy0;
    const float wx0 = 1.0f - wx1, wy0 = 1.0f - wy1;
    const bool vx0 = (x0 >= 0) && (x0 <= W_SZ - 1);
    const bool vx1 = (x0 + 1 >= 0) && (x0 + 1 <= W_SZ - 1);
    const bool vy0 = (y0 >= 0) && (y0 <= H_SZ - 1);
    const bool vy1 = (y0 + 1 >= 0) && (y0 + 1 <= H_SZ - 1);
    const float w00 = (vx0 && vy0) ? wx0 * wy0 : 0.0f;
    const float w01 = (vx1 && vy0) ? wx1 * wy0 : 0.0f;
    const float w10 = (vx0 && vy1) ? wx0 * wy1 : 0.0f;
    const float w11 = (vx1 && vy1) ? wx1 * wy1 : 0.0f;
    const int cx0 = min(max(x0, 0), W_SZ - 1);
    const int cx1 = min(max(x0 + 1, 0), W_SZ - 1);
    const int cy0 = min(max(y0, 0), H_SZ - 1);
    const int cy1 = min(max(y0 + 1, 0), H_SZ - 1);
    const int cx0p = min(cx0, W_SZ - 2);
    const bool l0 = (cx0 == cx0p);   // does cx0 sit in the LO slot?
    const bool l1 = (cx1 == cx0p);   // does cx1 sit in the LO slot?
    aw0 = (l0 ? w00 : 0.0f) + (l1 ? w01 : 0.0f);
    bw0 = (l0 ? 0.0f : w00) + (l1 ? 0.0f : w01);
    aw1 = (l0 ? w10 : 0.0f) + (l1 ? w11 : 0.0f);
    bw1 = (l0 ? 0.0f : w10) + (l1 ? 0.0f : w11);
    po0 = cy0 * W_SZ + cx0p;
    po1 = cy1 * W_SZ + cx0p;
}

template <typename T, typename OT>
__global__ __launch_bounds__(256, 4) void disconet_fused(
    const T* __restrict__ x, const T* __restrict__ ptm,
    const T* __restrict__ w1, const T* __restrict__ b1,
    const T* __restrict__ g1, const T* __restrict__ be1,
    const T* __restrict__ rm1, const T* __restrict__ rv1,
    const T* __restrict__ w2, const T* __restrict__ b2,
    const T* __restrict__ g2, const T* __restrict__ be2,
    const T* __restrict__ rm2, const T* __restrict__ rv2,
    const T* __restrict__ w3, const T* __restrict__ b3,
    const T* __restrict__ g3, const T* __restrict__ be3,
    const T* __restrict__ rm3, const T* __restrict__ rv3,
    const T* __restrict__ w4, const T* __restrict__ b4,
    const T* __restrict__ wm, const T* __restrict__ bm,
    OT* __restrict__ out, const int* __restrict__ flag, const int want)
{
    if (flag[0] != want) return;   // wave-uniform path select

    // 16B-aligned so weight rows can be read as float4 (ds_read_b128)
    __shared__ __align__(16) float s_w1[16 * 32];   // [o][0..15 nb | 16..31 ego]
    __shared__ float s_b1[16];
    __shared__ __align__(16) float s_w2[8 * 16];
    __shared__ float s_b2[8];
    __shared__ __align__(16) float s_w3[4 * 8];
    __shared__ float s_b3[4];
    __shared__ __align__(16) float s_w4v[4];
    __shared__ float s_b4;
    __shared__ __align__(16) float s_wm[16 * 16];
    __shared__ float s_bm[16];
    __shared__ float s_minv[L_AG][6];

    const int tid = threadIdx.x;

    // ---- block -> (ego, 2D tile), XCD-column + EGO-INNERMOST ordering ----
    // bid&7 = tile column (one 32px column per XCD assuming round-robin
    // bid->XCD). Within an XCD, consecutive blocks cycle through the 5 egos
    // of the SAME tile row -> warped variants share source lines while
    // co-resident; per-XCD L2 working set < 4MB -> x fetched ~once.
    const int bid      = blockIdx.x;
    const int tile_col = bid & 7;
    const int bp       = bid >> 3;        // 0..159
    const int i        = bp % L_AG;       // ego (inner)
    const int tile_row = bp / L_AG;       // 0..31 (outer)

    const int px_i = (tile_col << 5) + (tid & 31);   // 32x8 tile, coalesced rows
    const int py_i = (tile_row << 3) + (tid >> 5);
    const int p    = py_i * W_SZ + px_i;

    // ---- cooperative init: fold BN into conv weights ----
    for (int t = tid; t < 16 * 32; t += 256) {
        const int o = t >> 5;
        const float s = ldf(g1 + o) * rsqrtf(ldf(rv1 + o) + 1e-5f);
        s_w1[t] = ldf(w1 + t) * s;
    }
    if (tid < 128) {
        const int o = tid >> 4;
        const float s = ldf(g2 + o) * rsqrtf(ldf(rv2 + o) + 1e-5f);
        s_w2[tid] = ldf(w2 + tid) * s;
    }
    if (tid < 32) {
        const int o = tid >> 3;
        const float s = ldf(g3 + o) * rsqrtf(ldf(rv3 + o) + 1e-5f);
        s_w3[tid] = ldf(w3 + tid) * s;
    }
    if (tid < 16) {
        const float s1 = ldf(g1 + tid) * rsqrtf(ldf(rv1 + tid) + 1e-5f);
        s_b1[tid] = (ldf(b1 + tid) - ldf(rm1 + tid)) * s1 + ldf(be1 + tid);
        s_bm[tid] = ldf(bm + tid);
    }
    if (tid < 8) {
        const float s2 = ldf(g2 + tid) * rsqrtf(ldf(rv2 + tid) + 1e-5f);
        s_b2[tid] = (ldf(b2 + tid) - ldf(rm2 + tid)) * s2 + ldf(be2 + tid);
    }
    if (tid < 4) {
        const float s3 = ldf(g3 + tid) * rsqrtf(ldf(rv3 + tid) + 1e-5f);
        s_b3[tid] = (ldf(b3 + tid) - ldf(rm3 + tid)) * s3 + ldf(be3 + tid);
        s_w4v[tid] = ldf(w4 + tid);
    }
    if (tid == 0) s_b4 = ldf(b4);
    for (int t = tid; t < 256; t += 256) s_wm[t] = ldf(wm + t);

    if (tid < L_AG) {
        const int j = tid;
        const T* m = ptm + (j * L_AG + i) * 16;  // (1,L,L,4,4) row-major
        const float a  = ldf(m + 0);
        const float bb = ldf(m + 1);
        const float tx = ldf(m + 3) * 1.25f;     // / (0.4*2)
        const float c_ = ldf(m + 4);
        const float d  = ldf(m + 5);
        const float ty = ldf(m + 7) * 1.25f;
        float det = a * d - bb * c_;
        if (!(det > 1e-20f || det < -1e-20f)) det = 1.0f;  // guard: never Inf
        const float invdet = 1.0f / det;
        s_minv[j][0] =  d * invdet;
        s_minv[j][1] = -bb * invdet;
        s_minv[j][2] = (bb * ty - d * tx) * invdet;
        s_minv[j][3] = -c_ * invdet;
        s_minv[j][4] =  a * invdet;
        s_minv[j][5] = (c_ * tx - a * ty) * invdet;
    }
    __syncthreads();

    const float px = (float)px_i;
    const float py = (float)py_i;

    // ---- software-pipelined j-loop over pair taps ----
    // Plain unrolled float arrays with constant indices -> registers (proven
    // register-resident in R2 at VGPR=100; NO memcpy/addressable locals,
    // which in R4 demoted taps to scratch: WRITE_SIZE 20MB->237MB).
    // Two base offsets per j (po, po+1 folds into offset:4 immediate).
    float tl0[C_CH], th0[C_CH], tl1[C_CH], th1[C_CH];
    float caw0, cbw0, caw1, cbw1;

    // prologue: issue pair taps for j=0
    {
        int po0, po1;
        tap_params(s_minv, 0, px, py, po0, po1, caw0, cbw0, caw1, cbw1);
#pragma unroll
        for (int c = 0; c < C_CH; ++c) {
            const T* ic = x + c * HW_SZ;
            tl0[c] = ldf(ic + po0); th0[c] = ldf(ic + po0 + 1);
            tl1[c] = ldf(ic + po1); th1[c] = ldf(ic + po1 + 1);
        }
    }

    // ego contribution to layer 1 is j-invariant: hoist it.
    float h1b[16];
    {
        float ego[C_CH];
        const T* xp = x + i * C_CH * HW_SZ + p;
#pragma unroll
        for (int c = 0; c < C_CH; ++c) ego[c] = ldf(xp + c * HW_SZ);
#pragma unroll
        for (int o = 0; o < 16; ++o) {
            float a = s_b1[o];
#pragma unroll
            for (int k = 0; k < 4; ++k) {
                const float4 w = *reinterpret_cast<const float4*>(&s_w1[o * 32 + 16 + 4 * k]);
                a += w.x * ego[4 * k] + w.y * ego[4 * k + 1] +
                     w.z * ego[4 * k + 2] + w.w * ego[4 * k + 3];
            }
            h1b[o] = a;
        }
    }

    float acc[C_CH];
#pragma unroll
    for (int c = 0; c < C_CH; ++c) acc[c] = 0.0f;
    float lsum = 0.0f;

#pragma unroll 1
    for (int j = 0; j < L_AG; ++j) {
        // combine current pair taps (waits on in-flight loads)
        float nb[C_CH];
#pragma unroll
        for (int c = 0; c < C_CH; ++c)
            nb[c] = caw0 * tl0[c] + cbw0 * th0[c] +
                    caw1 * tl1[c] + cbw1 * th1[c];

        __builtin_amdgcn_sched_barrier(0);
        // issue next j's pair taps into the SAME registers; fly during MLP
        if (j + 1 < L_AG) {
            int po0, po1;
            tap_params(s_minv, j + 1, px, py, po0, po1, caw0, cbw0, caw1, cbw1);
            const T* img = x + (j + 1) * C_CH * HW_SZ;
#pragma unroll
            for (int c = 0; c < C_CH; ++c) {
                const T* ic = img + c * HW_SZ;
                tl0[c] = ldf(ic + po0); th0[c] = ldf(ic + po0 + 1);
                tl1[c] = ldf(ic + po1); th1[c] = ldf(ic + po1 + 1);
            }
        }
        __builtin_amdgcn_sched_barrier(0);

        // MLP (nb half of layer 1 only; ego half precomputed in h1b)
        float h1[16];
#pragma unroll
        for (int o = 0; o < 16; ++o) {
            float a = h1b[o];
#pragma unroll
            for (int k = 0; k < 4; ++k) {
                const float4 w = *reinterpret_cast<const float4*>(&s_w1[o * 32 + 4 * k]);
                a += w.x * nb[4 * k] + w.y * nb[4 * k + 1] +
                     w.z * nb[4 * k + 2] + w.w * nb[4 * k + 3];
            }
            h1[o] = fmaxf(a, 0.0f);
        }
        float h2[8];
#pragma unroll
        for (int o = 0; o < 8; ++o) {
            float a = s_b2[o];
#pragma unroll
            for (int k = 0; k < 4; ++k) {
                const float4 w = *reinterpret_cast<const float4*>(&s_w2[o * 16 + 4 * k]);
                a += w.x * h1[4 * k] + w.y * h1[4 * k + 1] +
                     w.z * h1[4 * k + 2] + w.w * h1[4 * k + 3];
            }
            h2[o] = fmaxf(a, 0.0f);
        }
        float h3[4];
#pragma unroll
        for (int o = 0; o < 4; ++o) {
            float a = s_b3[o];
#pragma unroll
            for (int k = 0; k < 2; ++k) {
                const float4 w = *reinterpret_cast<const float4*>(&s_w3[o * 8 + 4 * k]);
                a += w.x * h2[4 * k] + w.y * h2[4 * k + 1] +
                     w.z * h2[4 * k + 2] + w.w * h2[4 * k + 3];
            }
            h3[o] = fmaxf(a, 0.0f);
        }
        float sc = s_b4;
#pragma unroll
        for (int c = 0; c < 4; ++c) sc += s_w4v[c] * h3[c];
        sc = fminf(fmaxf(sc, 0.0f), 60.0f);  // relu + overflow guard

        const float es = __expf(sc);
        lsum += es;
#pragma unroll
        for (int c = 0; c < C_CH; ++c) acc[c] += es * nb[c];
    }

    const float invl = 1.0f / lsum;
#pragma unroll
    for (int c = 0; c < C_CH; ++c) acc[c] *= invl;

    OT* op = out + i * C_CH * HW_SZ + p;
#pragma unroll
    for (int o = 0; o < C_CH; ++o) {
        float a = s_bm[o];
#pragma unroll
        for (int k = 0; k < 4; ++k) {
            const float4 w = *reinterpret_cast<const float4*>(&s_wm[o * 16 + 4 * k]);
            a += w.x * acc[4 * k] + w.y * acc[4 * k + 1] +
                 w.z * acc[4 * k + 2] + w.w * acc[4 * k + 3];
        }
        stf(op + o * HW_SZ, a);
    }
}

extern "C" void kernel_launch(void* const* d_in, const int* in_sizes, int n_in,
                              void* d_out, int out_size, void* d_ws, size_t ws_size,
                              hipStream_t stream) {
    int* flag = (int*)d_ws;
    dtype_detect<<<1, 256, 0, stream>>>((const unsigned short*)d_in[0], flag);

    // 1280 blocks: 8 tile-cols x (5 egos inner x 32 tile-rows)
    dim3 grid(8 * 32 * L_AG);

    // bf16 path (flag==0)
    disconet_fused<bf16, bf16><<<grid, 256, 0, stream>>>(
        (const bf16*)d_in[0], (const bf16*)d_in[2],
        (const bf16*)d_in[3], (const bf16*)d_in[4],
        (const bf16*)d_in[5], (const bf16*)d_in[6],
        (const bf16*)d_in[7], (const bf16*)d_in[8],
        (const bf16*)d_in[9], (const bf16*)d_in[10],
        (const bf16*)d_in[11], (const bf16*)d_in[12],
        (const bf16*)d_in[13], (const bf16*)d_in[14],
        (const bf16*)d_in[15], (const bf16*)d_in[16],
        (const bf16*)d_in[17], (const bf16*)d_in[18],
        (const bf16*)d_in[19], (const bf16*)d_in[20],
        (const bf16*)d_in[21], (const bf16*)d_in[22],
        (const bf16*)d_in[23], (const bf16*)d_in[24],
        (bf16*)d_out, flag, 0);

    // fp32 path (flag==1)
    disconet_fused<float, float><<<grid, 256, 0, stream>>>(
        (const float*)d_in[0], (const float*)d_in[2],
        (const float*)d_in[3], (const float*)d_in[4],
        (const float*)d_in[5], (const float*)d_in[6],
        (const float*)d_in[7], (const float*)d_in[8],
        (const float*)d_in[9], (const float*)d_in[10],
        (const float*)d_in[11], (const float*)d_in[12],
        (const float*)d_in[13], (const float*)d_in[14],
        (const float*)d_in[15], (const float*)d_in[16],
        (const float*)d_in[17], (const float*)d_in[18],
        (const float*)d_in[19], (const float*)d_in[20],
        (const float*)d_in[21], (const float*)d_in[22],
        (const float*)d_in[23], (const float*)d_in[24],
        (float*)d_out, flag, 1);
}

// Round 6
// 193.328 us; speedup vs baseline: 1.4046x; 1.4046x over previous
//
#include <hip/hip_runtime.h>
#include <hip/hip_bf16.h>

typedef __hip_bfloat16 bf16;

#define L_AG 5
#define C_CH 16
#define H_SZ 256
#define W_SZ 256
#define HW_SZ (H_SZ * W_SZ)

// dtype-polymorphic load/store helpers
__device__ __forceinline__ float ldf(const float* p) { return *p; }
__device__ __forceinline__ float ldf(const bf16* p)  { return __bfloat162float(*p); }
__device__ __forceinline__ void  stf(float* p, float v) { *p = v; }
__device__ __forceinline__ void  stf(bf16* p, float v)  { *p = __float2bfloat16(v); }

// Runtime dtype detector: looks at even-indexed uint16 words of x.
// bf16 ~N(0,1): exponent field < 0x90 always (|v| >= 2^17 impossible).
// fp32 read as words: even words = random mantissa bits -> ~43% have exp >= 0x90.
__global__ void dtype_detect(const unsigned short* __restrict__ xw, int* __restrict__ flag) {
    __shared__ int cnt;
    if (threadIdx.x == 0) cnt = 0;
    __syncthreads();
    int h = 0;
    for (int t = threadIdx.x; t < 512; t += 256) {
        const unsigned short w = xw[2 * t];
        const int e = (w >> 7) & 0xFF;
        h += (e >= 0x90) ? 1 : 0;
    }
    atomicAdd(&cnt, h);
    __syncthreads();
    if (threadIdx.x == 0) flag[0] = (cnt >= 16) ? 1 : 0;  // 1 = fp32, 0 = bf16
}

// Inverse-affine taps for neighbor j as pair offsets (po0: row y0, po1: row
// y1, both at column base cx0p=min(cx0,W-2); the partner element is po+1)
// plus remapped bilinear weights (aw*lo + bw*hi per row). Exactly reproduces
// clamp+validity semantics:
//   interior: aw=w_left, bw=w_right
//   x0==255 : clamped value lives in HI slot -> bw=w00 (w01 already 0)
//   x0==-1  : clamped value lives in LO slot -> aw=w01 (w00 already 0)
__device__ __forceinline__ void tap_params(
    const float (*minv)[6], int j, float px, float py,
    int& po0, int& po1, float& aw0, float& bw0, float& aw1, float& bw1)
{
    const float m0 = minv[j][0], m1 = minv[j][1], m2 = minv[j][2];
    const float m3 = minv[j][3], m4 = minv[j][4], m5 = minv[j][5];
    const float sx = m0 * px + m1 * py + m2;
    const float sy = m3 * px + m4 * py + m5;
    const float fx0 = floorf(sx), fy0 = floorf(sy);
    const int x0 = (int)fx0, y0 = (int)fy0;
    const float wx1 = sx - fx0, wy1 = sy - fy0;
    const float wx0 = 1.0f - wx1, wy0 = 1.0f - wy1;
    const bool vx0 = (x0 >= 0) && (x0 <= W_SZ - 1);
    const bool vx1 = (x0 + 1 >= 0) && (x0 + 1 <= W_SZ - 1);
    const bool vy0 = (y0 >= 0) && (y0 <= H_SZ - 1);
    const bool vy1 = (y0 + 1 >= 0) && (y0 + 1 <= H_SZ - 1);
    const float w00 = (vx0 && vy0) ? wx0 * wy0 : 0.0f;
    const float w01 = (vx1 && vy0) ? wx1 * wy0 : 0.0f;
    const float w10 = (vx0 && vy1) ? wx0 * wy1 : 0.0f;
    const float w11 = (vx1 && vy1) ? wx1 * wy1 : 0.0f;
    const int cx0 = min(max(x0, 0), W_SZ - 1);
    const int cx1 = min(max(x0 + 1, 0), W_SZ - 1);
    const int cy0 = min(max(y0, 0), H_SZ - 1);
    const int cy1 = min(max(y0 + 1, 0), H_SZ - 1);
    const int cx0p = min(cx0, W_SZ - 2);
    const bool l0 = (cx0 == cx0p);   // does cx0 sit in the LO slot?
    const bool l1 = (cx1 == cx0p);   // does cx1 sit in the LO slot?
    aw0 = (l0 ? w00 : 0.0f) + (l1 ? w01 : 0.0f);
    bw0 = (l0 ? 0.0f : w00) + (l1 ? 0.0f : w01);
    aw1 = (l0 ? w10 : 0.0f) + (l1 ? w11 : 0.0f);
    bw1 = (l0 ? 0.0f : w10) + (l1 ? 0.0f : w11);
    po0 = cy0 * W_SZ + cx0p;
    po1 = cy1 * W_SZ + cx0p;
}

// __launch_bounds__(256,3): VGPR cap ~168. The pipeline's live set (64
// in-flight taps + h1b/acc/nb + transients) needs ~100-160 regs; a 4-wave
// bound (cap 128) forced ~50 regs/thread of scratch spill in R4/R5
// (WRITE_SIZE 20MB -> 284MB). 3 waves/SIMD is the no-spill occupancy max.
template <typename T, typename OT>
__global__ __launch_bounds__(256, 3) void disconet_fused(
    const T* __restrict__ x, const T* __restrict__ ptm,
    const T* __restrict__ w1, const T* __restrict__ b1,
    const T* __restrict__ g1, const T* __restrict__ be1,
    const T* __restrict__ rm1, const T* __restrict__ rv1,
    const T* __restrict__ w2, const T* __restrict__ b2,
    const T* __restrict__ g2, const T* __restrict__ be2,
    const T* __restrict__ rm2, const T* __restrict__ rv2,
    const T* __restrict__ w3, const T* __restrict__ b3,
    const T* __restrict__ g3, const T* __restrict__ be3,
    const T* __restrict__ rm3, const T* __restrict__ rv3,
    const T* __restrict__ w4, const T* __restrict__ b4,
    const T* __restrict__ wm, const T* __restrict__ bm,
    OT* __restrict__ out, const int* __restrict__ flag, const int want)
{
    if (flag[0] != want) return;   // wave-uniform path select

    // 16B-aligned so weight rows can be read as float4 (ds_read_b128)
    __shared__ __align__(16) float s_w1[16 * 32];   // [o][0..15 nb | 16..31 ego]
    __shared__ float s_b1[16];
    __shared__ __align__(16) float s_w2[8 * 16];
    __shared__ float s_b2[8];
    __shared__ __align__(16) float s_w3[4 * 8];
    __shared__ float s_b3[4];
    __shared__ __align__(16) float s_w4v[4];
    __shared__ float s_b4;
    __shared__ __align__(16) float s_wm[16 * 16];
    __shared__ float s_bm[16];
    __shared__ float s_minv[L_AG][6];

    const int tid = threadIdx.x;

    // ---- block -> (ego, 2D tile), XCD-column + EGO-INNERMOST ordering ----
    // bid&7 = tile column (one 32px column per XCD assuming round-robin
    // bid->XCD). Within an XCD, consecutive blocks cycle through the 5 egos
    // of the SAME tile row -> warped variants share source lines while
    // co-resident; per-XCD L2 working set < 4MB -> x fetched ~once.
    const int bid      = blockIdx.x;
    const int tile_col = bid & 7;
    const int bp       = bid >> 3;        // 0..159
    const int i        = bp % L_AG;       // ego (inner)
    const int tile_row = bp / L_AG;       // 0..31 (outer)

    const int px_i = (tile_col << 5) + (tid & 31);   // 32x8 tile, coalesced rows
    const int py_i = (tile_row << 3) + (tid >> 5);
    const int p    = py_i * W_SZ + px_i;

    // ---- cooperative init: fold BN into conv weights ----
    for (int t = tid; t < 16 * 32; t += 256) {
        const int o = t >> 5;
        const float s = ldf(g1 + o) * rsqrtf(ldf(rv1 + o) + 1e-5f);
        s_w1[t] = ldf(w1 + t) * s;
    }
    if (tid < 128) {
        const int o = tid >> 4;
        const float s = ldf(g2 + o) * rsqrtf(ldf(rv2 + o) + 1e-5f);
        s_w2[tid] = ldf(w2 + tid) * s;
    }
    if (tid < 32) {
        const int o = tid >> 3;
        const float s = ldf(g3 + o) * rsqrtf(ldf(rv3 + o) + 1e-5f);
        s_w3[tid] = ldf(w3 + tid) * s;
    }
    if (tid < 16) {
        const float s1 = ldf(g1 + tid) * rsqrtf(ldf(rv1 + tid) + 1e-5f);
        s_b1[tid] = (ldf(b1 + tid) - ldf(rm1 + tid)) * s1 + ldf(be1 + tid);
        s_bm[tid] = ldf(bm + tid);
    }
    if (tid < 8) {
        const float s2 = ldf(g2 + tid) * rsqrtf(ldf(rv2 + tid) + 1e-5f);
        s_b2[tid] = (ldf(b2 + tid) - ldf(rm2 + tid)) * s2 + ldf(be2 + tid);
    }
    if (tid < 4) {
        const float s3 = ldf(g3 + tid) * rsqrtf(ldf(rv3 + tid) + 1e-5f);
        s_b3[tid] = (ldf(b3 + tid) - ldf(rm3 + tid)) * s3 + ldf(be3 + tid);
        s_w4v[tid] = ldf(w4 + tid);
    }
    if (tid == 0) s_b4 = ldf(b4);
    for (int t = tid; t < 256; t += 256) s_wm[t] = ldf(wm + t);

    if (tid < L_AG) {
        const int j = tid;
        const T* m = ptm + (j * L_AG + i) * 16;  // (1,L,L,4,4) row-major
        const float a  = ldf(m + 0);
        const float bb = ldf(m + 1);
        const float tx = ldf(m + 3) * 1.25f;     // / (0.4*2)
        const float c_ = ldf(m + 4);
        const float d  = ldf(m + 5);
        const float ty = ldf(m + 7) * 1.25f;
        float det = a * d - bb * c_;
        if (!(det > 1e-20f || det < -1e-20f)) det = 1.0f;  // guard: never Inf
        const float invdet = 1.0f / det;
        s_minv[j][0] =  d * invdet;
        s_minv[j][1] = -bb * invdet;
        s_minv[j][2] = (bb * ty - d * tx) * invdet;
        s_minv[j][3] = -c_ * invdet;
        s_minv[j][4] =  a * invdet;
        s_minv[j][5] = (c_ * tx - a * ty) * invdet;
    }
    __syncthreads();

    const float px = (float)px_i;
    const float py = (float)py_i;

    // ---- software-pipelined j-loop over pair taps ----
    // Plain unrolled float arrays with constant indices -> registers.
    // Two base offsets per j (po, po+1 folds into an offset immediate).
    float tl0[C_CH], th0[C_CH], tl1[C_CH], th1[C_CH];
    float caw0, cbw0, caw1, cbw1;

    // prologue: issue pair taps for j=0
    {
        int po0, po1;
        tap_params(s_minv, 0, px, py, po0, po1, caw0, cbw0, caw1, cbw1);
#pragma unroll
        for (int c = 0; c < C_CH; ++c) {
            const T* ic = x + c * HW_SZ;
            tl0[c] = ldf(ic + po0); th0[c] = ldf(ic + po0 + 1);
            tl1[c] = ldf(ic + po1); th1[c] = ldf(ic + po1 + 1);
        }
    }

    // ego contribution to layer 1 is j-invariant: hoist it.
    float h1b[16];
    {
        float ego[C_CH];
        const T* xp = x + i * C_CH * HW_SZ + p;
#pragma unroll
        for (int c = 0; c < C_CH; ++c) ego[c] = ldf(xp + c * HW_SZ);
#pragma unroll
        for (int o = 0; o < 16; ++o) {
            float a = s_b1[o];
#pragma unroll
            for (int k = 0; k < 4; ++k) {
                const float4 w = *reinterpret_cast<const float4*>(&s_w1[o * 32 + 16 + 4 * k]);
                a += w.x * ego[4 * k] + w.y * ego[4 * k + 1] +
                     w.z * ego[4 * k + 2] + w.w * ego[4 * k + 3];
            }
            h1b[o] = a;
        }
    }

    float acc[C_CH];
#pragma unroll
    for (int c = 0; c < C_CH; ++c) acc[c] = 0.0f;
    float lsum = 0.0f;

#pragma unroll 1
    for (int j = 0; j < L_AG; ++j) {
        // combine current pair taps (waits on in-flight loads)
        float nb[C_CH];
#pragma unroll
        for (int c = 0; c < C_CH; ++c)
            nb[c] = caw0 * tl0[c] + cbw0 * th0[c] +
                    caw1 * tl1[c] + cbw1 * th1[c];

        __builtin_amdgcn_sched_barrier(0);
        // issue next j's pair taps into the SAME registers; fly during MLP
        if (j + 1 < L_AG) {
            int po0, po1;
            tap_params(s_minv, j + 1, px, py, po0, po1, caw0, cbw0, caw1, cbw1);
            const T* img = x + (j + 1) * C_CH * HW_SZ;
#pragma unroll
            for (int c = 0; c < C_CH; ++c) {
                const T* ic = img + c * HW_SZ;
                tl0[c] = ldf(ic + po0); th0[c] = ldf(ic + po0 + 1);
                tl1[c] = ldf(ic + po1); th1[c] = ldf(ic + po1 + 1);
            }
        }
        __builtin_amdgcn_sched_barrier(0);

        // MLP (nb half of layer 1 only; ego half precomputed in h1b)
        float h1[16];
#pragma unroll
        for (int o = 0; o < 16; ++o) {
            float a = h1b[o];
#pragma unroll
            for (int k = 0; k < 4; ++k) {
                const float4 w = *reinterpret_cast<const float4*>(&s_w1[o * 32 + 4 * k]);
                a += w.x * nb[4 * k] + w.y * nb[4 * k + 1] +
                     w.z * nb[4 * k + 2] + w.w * nb[4 * k + 3];
            }
            h1[o] = fmaxf(a, 0.0f);
        }
        float h2[8];
#pragma unroll
        for (int o = 0; o < 8; ++o) {
            float a = s_b2[o];
#pragma unroll
            for (int k = 0; k < 4; ++k) {
                const float4 w = *reinterpret_cast<const float4*>(&s_w2[o * 16 + 4 * k]);
                a += w.x * h1[4 * k] + w.y * h1[4 * k + 1] +
                     w.z * h1[4 * k + 2] + w.w * h1[4 * k + 3];
            }
            h2[o] = fmaxf(a, 0.0f);
        }
        float h3[4];
#pragma unroll
        for (int o = 0; o < 4; ++o) {
            float a = s_b3[o];
#pragma unroll
            for (int k = 0; k < 2; ++k) {
                const float4 w = *reinterpret_cast<const float4*>(&s_w3[o * 8 + 4 * k]);
                a += w.x * h2[4 * k] + w.y * h2[4 * k + 1] +
                     w.z * h2[4 * k + 2] + w.w * h2[4 * k + 3];
            }
            h3[o] = fmaxf(a, 0.0f);
        }
        float sc = s_b4;
#pragma unroll
        for (int c = 0; c < 4; ++c) sc += s_w4v[c] * h3[c];
        sc = fminf(fmaxf(sc, 0.0f), 60.0f);  // relu + overflow guard

        const float es = __expf(sc);
        lsum += es;
#pragma unroll
        for (int c = 0; c < C_CH; ++c) acc[c] += es * nb[c];
    }

    const float invl = 1.0f / lsum;
#pragma unroll
    for (int c = 0; c < C_CH; ++c) acc[c] *= invl;

    OT* op = out + i * C_CH * HW_SZ + p;
#pragma unroll
    for (int o = 0; o < C_CH; ++o) {
        float a = s_bm[o];
#pragma unroll
        for (int k = 0; k < 4; ++k) {
            const float4 w = *reinterpret_cast<const float4*>(&s_wm[o * 16 + 4 * k]);
            a += w.x * acc[4 * k] + w.y * acc[4 * k + 1] +
                 w.z * acc[4 * k + 2] + w.w * acc[4 * k + 3];
        }
        stf(op + o * HW_SZ, a);
    }
}

extern "C" void kernel_launch(void* const* d_in, const int* in_sizes, int n_in,
                              void* d_out, int out_size, void* d_ws, size_t ws_size,
                              hipStream_t stream) {
    int* flag = (int*)d_ws;
    dtype_detect<<<1, 256, 0, stream>>>((const unsigned short*)d_in[0], flag);

    // 1280 blocks: 8 tile-cols x (5 egos inner x 32 tile-rows)
    dim3 grid(8 * 32 * L_AG);

    // bf16 path (flag==0)
    disconet_fused<bf16, bf16><<<grid, 256, 0, stream>>>(
        (const bf16*)d_in[0], (const bf16*)d_in[2],
        (const bf16*)d_in[3], (const bf16*)d_in[4],
        (const bf16*)d_in[5], (const bf16*)d_in[6],
        (const bf16*)d_in[7], (const bf16*)d_in[8],
        (const bf16*)d_in[9], (const bf16*)d_in[10],
        (const bf16*)d_in[11], (const bf16*)d_in[12],
        (const bf16*)d_in[13], (const bf16*)d_in[14],
        (const bf16*)d_in[15], (const bf16*)d_in[16],
        (const bf16*)d_in[17], (const bf16*)d_in[18],
        (const bf16*)d_in[19], (const bf16*)d_in[20],
        (const bf16*)d_in[21], (const bf16*)d_in[22],
        (const bf16*)d_in[23], (const bf16*)d_in[24],
        (bf16*)d_out, flag, 0);

    // fp32 path (flag==1)
    disconet_fused<float, float><<<grid, 256, 0, stream>>>(
        (const float*)d_in[0], (const float*)d_in[2],
        (const float*)d_in[3], (const float*)d_in[4],
        (const float*)d_in[5], (const float*)d_in[6],
        (const float*)d_in[7], (const float*)d_in[8],
        (const float*)d_in[9], (const float*)d_in[10],
        (const float*)d_in[11], (const float*)d_in[12],
        (const float*)d_in[13], (const float*)d_in[14],
        (const float*)d_in[15], (const float*)d_in[16],
        (const float*)d_in[17], (const float*)d_in[18],
        (const float*)d_in[19], (const float*)d_in[20],
        (const float*)d_in[21], (const float*)d_in[22],
        (const float*)d_in[23], (const float*)d_in[24],
        (float*)d_out, flag, 1);
}